// Round 1
// baseline (861.649 us; speedup 1.0000x reference)
//
#include <hip/hip_runtime.h>
#include <math.h>

// Problem constants (from reference)
#define N_NEURONS 4096
#define N_INPUTS  8192
#define K         4
#define ROW_FLOATS   (N_INPUTS * K)      // 32768 floats per neuron row
#define ROW_VEC4     (ROW_FLOATS / 4)    // 8192 float4 per row
#define BLOCK_T      1024
#define VEC_PER_THR  (ROW_VEC4 / BLOCK_T) // 8 float4 per thread

#define DT_OVER_TAUV 0.05f   // DT / TAU_V = 0.01 / 0.2
#define ALPHA        0.5f
#define INV_TAU_W    0.02f   // 1 / 50

__global__ __launch_bounds__(BLOCK_T) void dv_bundle_kernel(
    const float* __restrict__ w,
    const float* __restrict__ x,
    const float* __restrict__ v,
    const float* __restrict__ r,
    float* __restrict__ out_v,
    float* __restrict__ out_r,
    float* __restrict__ out_w)
{
    const int n = blockIdx.x;          // one block per neuron row
    const int t = threadIdx.x;

    const float4* __restrict__ wrow = (const float4*)(w + (size_t)n * ROW_FLOATS);
    const float4* __restrict__ x4   = (const float4*)x;
    float4* __restrict__ owrow      = (float4*)(out_w + (size_t)n * ROW_FLOATS);

    // --- load row into registers, accumulate per-k partial dot products ---
    float4 wv[VEC_PER_THR];
    float4 acc = make_float4(0.f, 0.f, 0.f, 0.f);
#pragma unroll
    for (int u = 0; u < VEC_PER_THR; ++u) {
        const int j = t + u * BLOCK_T;          // coalesced across the wave
        wv[u] = wrow[j];
        float4 xv = x4[j];                       // x flat index == i*4+k layout
        acc.x += wv[u].x * xv.x;
        acc.y += wv[u].y * xv.y;
        acc.z += wv[u].z * xv.z;
        acc.w += wv[u].w * xv.w;
    }

    // --- wave (64-lane) butterfly reduce ---
#pragma unroll
    for (int off = 32; off > 0; off >>= 1) {
        acc.x += __shfl_down(acc.x, off);
        acc.y += __shfl_down(acc.y, off);
        acc.z += __shfl_down(acc.z, off);
        acc.w += __shfl_down(acc.w, off);
    }

    // --- cross-wave reduce via LDS (16 waves) ---
    __shared__ float4 smem[BLOCK_T / 64];
    __shared__ float4 I_sh;
    __shared__ float  g_sh;       // reg / TAU_W
    const int wave = t >> 6;
    const int lane = t & 63;
    if (lane == 0) smem[wave] = acc;
    __syncthreads();

    if (t == 0) {
        float4 I = smem[0];
#pragma unroll
        for (int i = 1; i < BLOCK_T / 64; ++i) {
            I.x += smem[i].x; I.y += smem[i].y; I.z += smem[i].z; I.w += smem[i].w;
        }
        const float vn = v[n];
        const float dv = (I.x - I.y + I.z - I.w - vn) * DT_OVER_TAUV;
        const float th = tanhf(vn);              // ACT_ALPHA = 1, THRES = 0
        const float actd = (vn > 0.f) ? (1.f - th * th) : 0.f;
        const float reg  = r[n] * actd * dv;
        I_sh = I;
        g_sh = reg * INV_TAU_W;
        out_v[n] = vn + dv;
        out_r[n] = (vn > 0.f) ? th : 0.f;
    }
    __syncthreads();

    const float4 I = I_sh;
    const float  g = g_sh;

    // --- update row from registers; re-read x (L2-hot, 128 KiB total) ---
#pragma unroll
    for (int u = 0; u < VEC_PER_THR; ++u) {
        const int j = t + u * BLOCK_T;
        float4 xv = x4[j];
        float4 o;
        o.x = wv[u].x + g * (xv.x * ALPHA - wv[u].x * I.x);
        o.y = wv[u].y + g * (xv.y * ALPHA - wv[u].y * I.y);
        o.z = wv[u].z + g * (xv.z * ALPHA - wv[u].z * I.z);
        o.w = wv[u].w + g * (xv.w * ALPHA - wv[u].w * I.w);
        owrow[j] = o;
    }
}

extern "C" void kernel_launch(void* const* d_in, const int* in_sizes, int n_in,
                              void* d_out, int out_size, void* d_ws, size_t ws_size,
                              hipStream_t stream) {
    const float* w = (const float*)d_in[0];   // [4096, 8192, 4]
    const float* x = (const float*)d_in[1];   // [8192, 4]
    const float* v = (const float*)d_in[2];   // [4096]
    const float* r = (const float*)d_in[3];   // [4096]

    float* out_v = (float*)d_out;                       // [4096]
    float* out_r = out_v + N_NEURONS;                   // [4096]
    float* out_w = out_r + N_NEURONS;                   // [4096, 8192, 4]

    dv_bundle_kernel<<<N_NEURONS, BLOCK_T, 0, stream>>>(w, x, v, r, out_v, out_r, out_w);
}